// Round 5
// baseline (937.112 us; speedup 1.0000x reference)
//
#include <hip/hip_runtime.h>
#include <hip/hip_bf16.h>

// H2GCN inference:
//   r0 = relu(x @ w_embed)                       [N,64]
//   r1 = relu([spmm(a1,r0) | spmm(a2,r0)])       [N,128]
//   r2 = relu([spmm(a1,r1) | spmm(a2,r1)])       [N,256]
//   out = softmax([r0|r1|r2] @ w_classify)       [N,16]
//
// SpMM: CSR bucketed by key = row*8 + column-slice (slice = col/6250, so a
// slice of the gathered input is 3.2 MB (hop2) / 1.6 MB (hop1) -- fits the
// 4 MB per-XCD L2). SpMM is PERSISTENT: each wave owns 13 output rows for
// BOTH graphs (equal per-slice work -> waves sweep slices in near-lockstep;
// grid fully resident so no block turnover). Each XCD then fetches each
// input slice ~once instead of missing 43-85% of random gathers (round-4
// counters: both hops 155us, FETCH 524MB, VALUBusy 19% = L2-capacity bound).

#define F_IN 256
#define H_DIM 64
#define S_SL 8      // column slices
#define R_PW 13     // rows per wave in persistent spmm

// ---------------- embed GEMM: r0 = relu(x @ w) ----------------
__global__ __launch_bounds__(256) void embed_gemm_relu(
    const float* __restrict__ x, const float* __restrict__ w,
    float* __restrict__ r0, int n_tiles) {
  __shared__ float ws[F_IN * H_DIM];  // 64 KB
  for (int i = threadIdx.x; i < F_IN * H_DIM / 4; i += 256)
    ((float4*)ws)[i] = ((const float4*)w)[i];
  __syncthreads();
  int lane = threadIdx.x & 63;
  int tile = blockIdx.x * 4 + (threadIdx.x >> 6);
  if (tile >= n_tiles) return;
  int row = tile * 4;
  float xv[4][4];
#pragma unroll
  for (int j = 0; j < 4; ++j)
#pragma unroll
    for (int q = 0; q < 4; ++q)
      xv[j][q] = x[(size_t)(row + j) * F_IN + q * 64 + lane];
  float acc[4] = {0.f, 0.f, 0.f, 0.f};
#pragma unroll
  for (int k = 0; k < 256; ++k) {
    float wk = ws[k * 64 + lane];
#pragma unroll
    for (int j = 0; j < 4; ++j) {
      float xb = __uint_as_float(
          __builtin_amdgcn_readlane(__float_as_uint(xv[j][k >> 6]), k & 63));
      acc[j] = fmaf(xb, wk, acc[j]);
    }
  }
#pragma unroll
  for (int j = 0; j < 4; ++j)
    r0[(size_t)(row + j) * H_DIM + lane] = fmaxf(acc[j], 0.f);
}

__device__ __forceinline__ int slice_of(int c, float inv) {
  int sl = (int)((float)c * inv);
  return sl < S_SL - 1 ? sl : S_SL - 1;
}

// ---------------- CSR build (key = row*S + slice) ----------------------
__global__ __launch_bounds__(256) void histo2(
    const int* __restrict__ i1, int E1, int* __restrict__ c1,
    const int* __restrict__ i2, int E2, int* __restrict__ c2, int HB1,
    float inv) {
  int b = blockIdx.x;
  if (b < HB1) {
    int i = b * 256 + threadIdx.x;
    if (i < E1) atomicAdd(&c1[i1[i] * S_SL + slice_of(i1[E1 + i], inv)], 1);
  } else {
    int i = (b - HB1) * 256 + threadIdx.x;
    if (i < E2) atomicAdd(&c2[i2[i] * S_SL + slice_of(i2[E2 + i], inv)], 1);
  }
}

// exclusive scan, level 1: 1024-element blocks; both graphs in one grid
__global__ __launch_bounds__(1024) void scan_blocks2(
    const int* __restrict__ c1, int* __restrict__ e1, int* __restrict__ a1,
    const int* __restrict__ c2, int* __restrict__ e2, int* __restrict__ a2,
    int m, int NB) {
  const int* cnt;
  int* exc;
  int* aux;
  int blk = blockIdx.x;
  if (blk < NB) {
    cnt = c1; exc = e1; aux = a1;
  } else {
    cnt = c2; exc = e2; aux = a2; blk -= NB;
  }
  __shared__ int tmp[1024];
  int i = blk * 1024 + threadIdx.x;
  int v = (i < m) ? cnt[i] : 0;
  tmp[threadIdx.x] = v;
  __syncthreads();
  for (int d = 1; d < 1024; d <<= 1) {
    int t = (threadIdx.x >= (unsigned)d) ? tmp[threadIdx.x - d] : 0;
    __syncthreads();
    tmp[threadIdx.x] += t;
    __syncthreads();
  }
  if (i < m) exc[i] = tmp[threadIdx.x] - v;
  if (threadIdx.x == 1023) aux[blk] = tmp[1023];
}

// exclusive scan, level 2 (NB <= 1024): block 0 -> aux1, block 1 -> aux2
__global__ __launch_bounds__(1024) void scan_aux2(int* __restrict__ a1,
                                                  int* __restrict__ a2,
                                                  int nblk) {
  int* aux = (blockIdx.x == 0) ? a1 : a2;
  __shared__ int tmp[1024];
  int v = (threadIdx.x < (unsigned)nblk) ? aux[threadIdx.x] : 0;
  tmp[threadIdx.x] = v;
  __syncthreads();
  for (int d = 1; d < 1024; d <<= 1) {
    int t = (threadIdx.x >= (unsigned)d) ? tmp[threadIdx.x - d] : 0;
    __syncthreads();
    tmp[threadIdx.x] += t;
    __syncthreads();
  }
  if (threadIdx.x < (unsigned)nblk) aux[threadIdx.x] = tmp[threadIdx.x] - v;
}

__global__ __launch_bounds__(1024) void add_offsets2(
    int* __restrict__ rs1, int* __restrict__ cur1, const int* __restrict__ a1,
    int E1, int* __restrict__ rs2, int* __restrict__ cur2,
    const int* __restrict__ a2, int E2, int m, int NB) {
  int blk = blockIdx.x;
  int* rs;
  int* cur;
  const int* aux;
  int E;
  if (blk < NB) {
    rs = rs1; cur = cur1; aux = a1; E = E1;
  } else {
    rs = rs2; cur = cur2; aux = a2; E = E2; blk -= NB;
  }
  int i = blk * 1024 + threadIdx.x;
  if (i < m) {
    int v = rs[i] + aux[blk];
    rs[i] = v;
    cur[i] = v;
  }
  if (blk == 0 && threadIdx.x == 0) rs[m] = E;
}

// XCD-range-partitioned scatter (group g = blockIdx&7 owns one row range ->
// each epack cache line written by one XCD). Packed int2 (col,val).
__global__ __launch_bounds__(256) void scatter_ranged(
    const int* __restrict__ i1, const float* __restrict__ v1, int E1,
    int* __restrict__ cur1, int2* __restrict__ ep1,
    const int* __restrict__ i2, const float* __restrict__ v2, int E2,
    int* __restrict__ cur2, int2* __restrict__ ep2, int SB1, int SBtot,
    int n, float inv) {
  int b = blockIdx.x;
  const int* I;
  const float* V;
  int E, nb;
  int* cur;
  int2* ep;
  if (b < SB1) {
    I = i1; V = v1; E = E1; cur = cur1; ep = ep1; nb = SB1;
  } else {
    I = i2; V = v2; E = E2; cur = cur2; ep = ep2; nb = SBtot - SB1; b -= SB1;
  }
  int g = b & 7;
  int bg = b >> 3;
  int chunk = (n + 7) >> 3;
  int lo = g * chunk;
  int hi = min(n, lo + chunk);
  int stride = (nb >> 3) * 256;
  for (int i = bg * 256 + threadIdx.x; i < E; i += stride) {
    int r = I[i];
    int c = I[E + i];
    float v = V[i];
    if (r >= lo && r < hi) {
      int p = atomicAdd(&cur[r * S_SL + slice_of(c, inv)], 1);
      int2 pk;
      pk.x = c;
      pk.y = __float_as_int(v);
      ep[p] = pk;
    }
  }
}

// ---------------- persistent slice-synced SpMM ------------------------
// hop1: input r0 [n,64], output r1 [n,128] = [g1 | g2], ReLU fused.
__global__ __launch_bounds__(256, 4) void spmm_hop1(
    const int* __restrict__ rsk1, const int2* __restrict__ ep1,
    const int* __restrict__ rsk2, const int2* __restrict__ ep2,
    const float* __restrict__ r0, float* __restrict__ r1, int n) {
  int lane = threadIdx.x & 63;
  int wid = blockIdx.x * 4 + (threadIdx.x >> 6);
  int lo = wid * R_PW;
  float a1[R_PW], a2[R_PW];
#pragma unroll
  for (int r = 0; r < R_PW; ++r) {
    a1[r] = 0.f;
    a2[r] = 0.f;
  }
  for (int s = 0; s < S_SL; ++s) {
#pragma unroll
    for (int r = 0; r < R_PW; ++r) {
      int row = lo + r;
      if (row < n) {
        int key = row * S_SL + s;
        {
          int je = rsk1[key + 1];
          int j = rsk1[key];
          for (; j + 4 <= je; j += 4) {
            int2 e0 = ep1[j], e1 = ep1[j + 1], e2 = ep1[j + 2], e3 = ep1[j + 3];
            float x0 = r0[(size_t)e0.x * 64 + lane];
            float x1 = r0[(size_t)e1.x * 64 + lane];
            float x2 = r0[(size_t)e2.x * 64 + lane];
            float x3 = r0[(size_t)e3.x * 64 + lane];
            a1[r] = fmaf(__int_as_float(e0.y), x0, a1[r]);
            a1[r] = fmaf(__int_as_float(e1.y), x1, a1[r]);
            a1[r] = fmaf(__int_as_float(e2.y), x2, a1[r]);
            a1[r] = fmaf(__int_as_float(e3.y), x3, a1[r]);
          }
          for (; j < je; ++j) {
            int2 e = ep1[j];
            a1[r] = fmaf(__int_as_float(e.y), r0[(size_t)e.x * 64 + lane], a1[r]);
          }
        }
        {
          int je = rsk2[key + 1];
          int j = rsk2[key];
          for (; j + 4 <= je; j += 4) {
            int2 e0 = ep2[j], e1 = ep2[j + 1], e2 = ep2[j + 2], e3 = ep2[j + 3];
            float x0 = r0[(size_t)e0.x * 64 + lane];
            float x1 = r0[(size_t)e1.x * 64 + lane];
            float x2 = r0[(size_t)e2.x * 64 + lane];
            float x3 = r0[(size_t)e3.x * 64 + lane];
            a2[r] = fmaf(__int_as_float(e0.y), x0, a2[r]);
            a2[r] = fmaf(__int_as_float(e1.y), x1, a2[r]);
            a2[r] = fmaf(__int_as_float(e2.y), x2, a2[r]);
            a2[r] = fmaf(__int_as_float(e3.y), x3, a2[r]);
          }
          for (; j < je; ++j) {
            int2 e = ep2[j];
            a2[r] = fmaf(__int_as_float(e.y), r0[(size_t)e.x * 64 + lane], a2[r]);
          }
        }
      }
    }
  }
#pragma unroll
  for (int r = 0; r < R_PW; ++r) {
    int row = lo + r;
    if (row < n) {
      r1[(size_t)row * 128 + lane] = fmaxf(a1[r], 0.f);
      r1[(size_t)row * 128 + 64 + lane] = fmaxf(a2[r], 0.f);
    }
  }
}

// hop2: input r1 [n,128], output r2 [n,256] = [g1 | g2], ReLU fused.
__global__ __launch_bounds__(256, 4) void spmm_hop2(
    const int* __restrict__ rsk1, const int2* __restrict__ ep1,
    const int* __restrict__ rsk2, const int2* __restrict__ ep2,
    const float* __restrict__ r1, float* __restrict__ r2, int n) {
  int lane = threadIdx.x & 63;
  int wid = blockIdx.x * 4 + (threadIdx.x >> 6);
  int lo = wid * R_PW;
  float2 a1[R_PW], a2[R_PW];
#pragma unroll
  for (int r = 0; r < R_PW; ++r) {
    a1[r] = make_float2(0.f, 0.f);
    a2[r] = make_float2(0.f, 0.f);
  }
  for (int s = 0; s < S_SL; ++s) {
#pragma unroll
    for (int r = 0; r < R_PW; ++r) {
      int row = lo + r;
      if (row < n) {
        int key = row * S_SL + s;
        {
          int je = rsk1[key + 1];
          int j = rsk1[key];
          for (; j + 4 <= je; j += 4) {
            int2 e0 = ep1[j], e1 = ep1[j + 1], e2 = ep1[j + 2], e3 = ep1[j + 3];
            float2 x0 = *(const float2*)&r1[(size_t)e0.x * 128 + lane * 2];
            float2 x1 = *(const float2*)&r1[(size_t)e1.x * 128 + lane * 2];
            float2 x2 = *(const float2*)&r1[(size_t)e2.x * 128 + lane * 2];
            float2 x3 = *(const float2*)&r1[(size_t)e3.x * 128 + lane * 2];
            float v0 = __int_as_float(e0.y), v1 = __int_as_float(e1.y);
            float v2 = __int_as_float(e2.y), v3 = __int_as_float(e3.y);
            a1[r].x = fmaf(v0, x0.x, a1[r].x);
            a1[r].y = fmaf(v0, x0.y, a1[r].y);
            a1[r].x = fmaf(v1, x1.x, a1[r].x);
            a1[r].y = fmaf(v1, x1.y, a1[r].y);
            a1[r].x = fmaf(v2, x2.x, a1[r].x);
            a1[r].y = fmaf(v2, x2.y, a1[r].y);
            a1[r].x = fmaf(v3, x3.x, a1[r].x);
            a1[r].y = fmaf(v3, x3.y, a1[r].y);
          }
          for (; j < je; ++j) {
            int2 e = ep1[j];
            float2 xv = *(const float2*)&r1[(size_t)e.x * 128 + lane * 2];
            float v = __int_as_float(e.y);
            a1[r].x = fmaf(v, xv.x, a1[r].x);
            a1[r].y = fmaf(v, xv.y, a1[r].y);
          }
        }
        {
          int je = rsk2[key + 1];
          int j = rsk2[key];
          for (; j + 4 <= je; j += 4) {
            int2 e0 = ep2[j], e1 = ep2[j + 1], e2 = ep2[j + 2], e3 = ep2[j + 3];
            float2 x0 = *(const float2*)&r1[(size_t)e0.x * 128 + lane * 2];
            float2 x1 = *(const float2*)&r1[(size_t)e1.x * 128 + lane * 2];
            float2 x2 = *(const float2*)&r1[(size_t)e2.x * 128 + lane * 2];
            float2 x3 = *(const float2*)&r1[(size_t)e3.x * 128 + lane * 2];
            float v0 = __int_as_float(e0.y), v1 = __int_as_float(e1.y);
            float v2 = __int_as_float(e2.y), v3 = __int_as_float(e3.y);
            a2[r].x = fmaf(v0, x0.x, a2[r].x);
            a2[r].y = fmaf(v0, x0.y, a2[r].y);
            a2[r].x = fmaf(v1, x1.x, a2[r].x);
            a2[r].y = fmaf(v1, x1.y, a2[r].y);
            a2[r].x = fmaf(v2, x2.x, a2[r].x);
            a2[r].y = fmaf(v2, x2.y, a2[r].y);
            a2[r].x = fmaf(v3, x3.x, a2[r].x);
            a2[r].y = fmaf(v3, x3.y, a2[r].y);
          }
          for (; j < je; ++j) {
            int2 e = ep2[j];
            float2 xv = *(const float2*)&r1[(size_t)e.x * 128 + lane * 2];
            float v = __int_as_float(e.y);
            a2[r].x = fmaf(v, xv.x, a2[r].x);
            a2[r].y = fmaf(v, xv.y, a2[r].y);
          }
        }
      }
    }
  }
#pragma unroll
  for (int r = 0; r < R_PW; ++r) {
    int row = lo + r;
    if (row < n) {
      float2 s1, s2;
      s1.x = fmaxf(a1[r].x, 0.f);
      s1.y = fmaxf(a1[r].y, 0.f);
      s2.x = fmaxf(a2[r].x, 0.f);
      s2.y = fmaxf(a2[r].y, 0.f);
      *(float2*)&r2[(size_t)row * 256 + lane * 2] = s1;
      *(float2*)&r2[(size_t)row * 256 + 128 + lane * 2] = s2;
    }
  }
}

// ---------------- classifier + softmax --------------------------------
__global__ __launch_bounds__(256) void classify_softmax(
    const float* __restrict__ r0, const float* __restrict__ r1,
    const float* __restrict__ r2, const float* __restrict__ wc,
    float* __restrict__ out, int n) {
  __shared__ float wls[448 * 16];  // 28 KB
  for (int i = threadIdx.x; i < 448 * 16 / 4; i += 256)
    ((float4*)wls)[i] = ((const float4*)wc)[i];
  __syncthreads();
  int lane = threadIdx.x & 63;
  int c = lane & 15;
  int part = lane >> 4;
  int node = blockIdx.x * 4 + (threadIdx.x >> 6);
  if (node >= n) return;

  float acc = 0.f;
  {
    const float* p = r0 + (size_t)node * 64 + part * 16;
#pragma unroll
    for (int j = 0; j < 4; ++j) {
      float4 rv = *(const float4*)(p + 4 * j);
      int fb = part * 16 + 4 * j;
      acc = fmaf(rv.x, wls[(fb + 0) * 16 + c], acc);
      acc = fmaf(rv.y, wls[(fb + 1) * 16 + c], acc);
      acc = fmaf(rv.z, wls[(fb + 2) * 16 + c], acc);
      acc = fmaf(rv.w, wls[(fb + 3) * 16 + c], acc);
    }
  }
  {
    const float* p = r1 + (size_t)node * 128 + part * 32;
#pragma unroll
    for (int j = 0; j < 8; ++j) {
      float4 rv = *(const float4*)(p + 4 * j);
      int fb = 64 + part * 32 + 4 * j;
      acc = fmaf(rv.x, wls[(fb + 0) * 16 + c], acc);
      acc = fmaf(rv.y, wls[(fb + 1) * 16 + c], acc);
      acc = fmaf(rv.z, wls[(fb + 2) * 16 + c], acc);
      acc = fmaf(rv.w, wls[(fb + 3) * 16 + c], acc);
    }
  }
  {
    const float* p = r2 + (size_t)node * 256 + part * 64;
#pragma unroll
    for (int j = 0; j < 16; ++j) {
      float4 rv = *(const float4*)(p + 4 * j);
      int fb = 192 + part * 64 + 4 * j;
      acc = fmaf(rv.x, wls[(fb + 0) * 16 + c], acc);
      acc = fmaf(rv.y, wls[(fb + 1) * 16 + c], acc);
      acc = fmaf(rv.z, wls[(fb + 2) * 16 + c], acc);
      acc = fmaf(rv.w, wls[(fb + 3) * 16 + c], acc);
    }
  }
  acc += __shfl_xor(acc, 16, 64);
  acc += __shfl_xor(acc, 32, 64);
  float m = acc;
#pragma unroll
  for (int d = 1; d < 16; d <<= 1) m = fmaxf(m, __shfl_xor(m, d, 64));
  float ex = __expf(acc - m);
  float s = ex;
#pragma unroll
  for (int d = 1; d < 16; d <<= 1) s += __shfl_xor(s, d, 64);
  if (lane < 16) out[(size_t)node * 16 + c] = ex / s;
}

extern "C" void kernel_launch(void* const* d_in, const int* in_sizes, int n_in,
                              void* d_out, int out_size, void* d_ws, size_t ws_size,
                              hipStream_t stream) {
  const float* x = (const float*)d_in[0];
  const int* a1_idx = (const int*)d_in[1];
  const float* a1_val = (const float*)d_in[2];
  const int* a2_idx = (const int*)d_in[3];
  const float* a2_val = (const float*)d_in[4];
  const float* w_embed = (const float*)d_in[5];
  const float* w_classify = (const float*)d_in[6];
  float* out = (float*)d_out;

  const int n = in_sizes[0] / F_IN;  // 50000
  const int E1 = in_sizes[2];        // 800000
  const int E2 = in_sizes[4];        // 1600000
  const int m = n * S_SL;            // key-space size per graph
  const int slice_sz = (n + S_SL - 1) / S_SL;
  const float inv = 1.0f / (float)slice_sz;

  // workspace layout
  float* r0 = (float*)d_ws;                  // n*64
  float* r1 = r0 + (size_t)n * 64;           // n*128
  float* r2 = r1 + (size_t)n * 128;          // n*256
  int* cnt1 = (int*)(r2 + (size_t)n * 256);  // m (doubles as cur1)
  int* cnt2 = cnt1 + m;                      // m (doubles as cur2)
  int* rsk1 = cnt2 + m;                      // m+1
  int* rsk2 = rsk1 + (m + 1);                // m+1
  int* aux1 = rsk2 + (m + 1);                // 1024
  int* aux2 = aux1 + 1024;                   // 1024
  int2* ep1 = (int2*)(aux2 + 1024);          // E1 (8B each)
  int2* ep2 = ep1 + E1;                      // E2

  auto blocks = [](long long t, int bs) { return (int)((t + bs - 1) / bs); };
  const int NB = blocks(m, 1024);        // 391 <= 1024
  const int HB1 = blocks(E1, 256);       // 3125
  const int HB2 = blocks(E2, 256);       // 6250
  const int SC1 = 1024, SC2 = 2048;      // scatter blocks (mult of 8)
  const int WAVES = blocks(n, R_PW);     // 3847 persistent waves
  const int PB = blocks(WAVES, 4);       // 962 blocks (all resident)

  // embed (independent of CSR build)
  embed_gemm_relu<<<blocks(n / 4, 4), 256, 0, stream>>>(x, w_embed, r0, n / 4);

  // CSR build (key = row*8 + slice) for both graphs
  hipMemsetAsync(cnt1, 0, (size_t)2 * m * sizeof(int), stream);
  histo2<<<HB1 + HB2, 256, 0, stream>>>(a1_idx, E1, cnt1, a2_idx, E2, cnt2,
                                        HB1, inv);
  scan_blocks2<<<2 * NB, 1024, 0, stream>>>(cnt1, rsk1, aux1, cnt2, rsk2, aux2,
                                            m, NB);
  scan_aux2<<<2, 1024, 0, stream>>>(aux1, aux2, NB);
  add_offsets2<<<2 * NB, 1024, 0, stream>>>(rsk1, cnt1, aux1, E1, rsk2, cnt2,
                                            aux2, E2, m, NB);
  scatter_ranged<<<SC1 + SC2, 256, 0, stream>>>(a1_idx, a1_val, E1, cnt1, ep1,
                                                a2_idx, a2_val, E2, cnt2, ep2,
                                                SC1, SC1 + SC2, n, inv);

  // hop 1: r0 [n,64] -> r1 [n,128]  (persistent, slice-synced, ReLU fused)
  spmm_hop1<<<PB, 256, 0, stream>>>(rsk1, ep1, rsk2, ep2, r0, r1, n);
  // hop 2: r1 [n,128] -> r2 [n,256]
  spmm_hop2<<<PB, 256, 0, stream>>>(rsk1, ep1, rsk2, ep2, r1, r2, n);

  classify_softmax<<<blocks(n, 4), 256, 0, stream>>>(r0, r1, r2, w_classify, out, n);
}

// Round 7
// 524.332 us; speedup vs baseline: 1.7872x; 1.7872x over previous
//
#include <hip/hip_runtime.h>
#include <hip/hip_bf16.h>
#include <hip/hip_fp16.h>

// H2GCN inference:
//   r0 = relu(x @ w_embed)                       [N,64]
//   r1 = relu([spmm(a1,r0) | spmm(a2,r0)])       [N,128]
//   r2 = relu([spmm(a1,r1) | spmm(a2,r1)])       [N,256]
//   out = softmax([r0|r1|r2] @ w_classify)       [N,16]
//
// Round-7: flat CSR gather SpMM (round-4 structure: wave/row, 8-deep MLP,
// 73% occupancy); gathers read FP16 mirrors of r0/r1 (f32 accumulate, f32
// outputs kept for the classifier). Halves gather bytes and random working
// set. bf16 mirrors (round 6) failed absmax 0.035 > 0.02; fp16 has 8x
// less mantissa error -> predicted ~0.005. Round-5 slice-bucketing stays
// reverted (fragmentation made it latency-bound).

#define F_IN 256
#define H_DIM 64

__device__ __forceinline__ unsigned short f2h(float x) {
  return __half_as_ushort(__float2half(x));  // RNE v_cvt_f16_f32
}
__device__ __forceinline__ float h2f(unsigned short u) {
  return __half2float(__ushort_as_half(u));
}

// ---------------- embed GEMM: r0 = relu(x @ w), + f16 mirror ----------
__global__ __launch_bounds__(256) void embed_gemm_relu(
    const float* __restrict__ x, const float* __restrict__ w,
    float* __restrict__ r0, unsigned short* __restrict__ r0h, int n_tiles) {
  __shared__ float ws[F_IN * H_DIM];  // 64 KB
  for (int i = threadIdx.x; i < F_IN * H_DIM / 4; i += 256)
    ((float4*)ws)[i] = ((const float4*)w)[i];
  __syncthreads();
  int lane = threadIdx.x & 63;
  int tile = blockIdx.x * 4 + (threadIdx.x >> 6);
  if (tile >= n_tiles) return;
  int row = tile * 4;
  float xv[4][4];
#pragma unroll
  for (int j = 0; j < 4; ++j)
#pragma unroll
    for (int q = 0; q < 4; ++q)
      xv[j][q] = x[(size_t)(row + j) * F_IN + q * 64 + lane];
  float acc[4] = {0.f, 0.f, 0.f, 0.f};
#pragma unroll
  for (int k = 0; k < 256; ++k) {
    float wk = ws[k * 64 + lane];
#pragma unroll
    for (int j = 0; j < 4; ++j) {
      float xb = __uint_as_float(
          __builtin_amdgcn_readlane(__float_as_uint(xv[j][k >> 6]), k & 63));
      acc[j] = fmaf(xb, wk, acc[j]);
    }
  }
#pragma unroll
  for (int j = 0; j < 4; ++j) {
    float v = fmaxf(acc[j], 0.f);
    r0[(size_t)(row + j) * H_DIM + lane] = v;
    r0h[(size_t)(row + j) * H_DIM + lane] = f2h(v);
  }
}

// ---------------- CSR build (both graphs fused per stage) ---------------
__global__ __launch_bounds__(256) void histo2(
    const int* __restrict__ i1, int E1, int* __restrict__ c1,
    const int* __restrict__ i2, int E2, int* __restrict__ c2, int HB1) {
  int b = blockIdx.x;
  if (b < HB1) {
    int i = b * 256 + threadIdx.x;
    if (i < E1) atomicAdd(&c1[i1[i]], 1);
  } else {
    int i = (b - HB1) * 256 + threadIdx.x;
    if (i < E2) atomicAdd(&c2[i2[i]], 1);
  }
}

__global__ __launch_bounds__(512) void scan_blocks2(
    const int* __restrict__ c1, int* __restrict__ e1, int* __restrict__ a1,
    const int* __restrict__ c2, int* __restrict__ e2, int* __restrict__ a2,
    int n, int NB) {
  const int* cnt;
  int* exc;
  int* aux;
  int blk = blockIdx.x;
  if (blk < NB) {
    cnt = c1; exc = e1; aux = a1;
  } else {
    cnt = c2; exc = e2; aux = a2; blk -= NB;
  }
  __shared__ int tmp[512];
  int i = blk * 512 + threadIdx.x;
  int v = (i < n) ? cnt[i] : 0;
  tmp[threadIdx.x] = v;
  __syncthreads();
#pragma unroll
  for (int d = 1; d < 512; d <<= 1) {
    int t = (threadIdx.x >= d) ? tmp[threadIdx.x - d] : 0;
    __syncthreads();
    tmp[threadIdx.x] += t;
    __syncthreads();
  }
  if (i < n) exc[i] = tmp[threadIdx.x] - v;
  if (threadIdx.x == 511) aux[blk] = tmp[511];
}

__global__ __launch_bounds__(512) void scan_aux2(int* __restrict__ a1,
                                                 int* __restrict__ a2,
                                                 int nblk) {
  int* aux = (blockIdx.x == 0) ? a1 : a2;
  __shared__ int tmp[512];
  int v = (threadIdx.x < nblk) ? aux[threadIdx.x] : 0;
  tmp[threadIdx.x] = v;
  __syncthreads();
#pragma unroll
  for (int d = 1; d < 512; d <<= 1) {
    int t = (threadIdx.x >= d) ? tmp[threadIdx.x - d] : 0;
    __syncthreads();
    tmp[threadIdx.x] += t;
    __syncthreads();
  }
  if (threadIdx.x < nblk) aux[threadIdx.x] = tmp[threadIdx.x] - v;
}

__global__ __launch_bounds__(512) void add_offsets2(
    int* __restrict__ rs1, int* __restrict__ cur1, const int* __restrict__ a1,
    int E1, int* __restrict__ rs2, int* __restrict__ cur2,
    const int* __restrict__ a2, int E2, int n, int NB) {
  int blk = blockIdx.x;
  int* rs;
  int* cur;
  const int* aux;
  int E;
  if (blk < NB) {
    rs = rs1; cur = cur1; aux = a1; E = E1;
  } else {
    rs = rs2; cur = cur2; aux = a2; E = E2; blk -= NB;
  }
  int i = blk * 512 + threadIdx.x;
  if (i < n) {
    int v = rs[i] + aux[blk];
    rs[i] = v;
    cur[i] = v;
  }
  if (blk == 0 && threadIdx.x == 0) rs[n] = E;
}

// XCD-range-partitioned scatter (group g = blockIdx&7 owns one row range ->
// each epack cache line written by one XCD). Packed int2 (col,val).
__global__ __launch_bounds__(256) void scatter_ranged(
    const int* __restrict__ i1, const float* __restrict__ v1, int E1,
    int* __restrict__ cur1, int2* __restrict__ ep1,
    const int* __restrict__ i2, const float* __restrict__ v2, int E2,
    int* __restrict__ cur2, int2* __restrict__ ep2, int SB1, int SBtot,
    int n) {
  int b = blockIdx.x;
  const int* I;
  const float* V;
  int E, nb;
  int* cur;
  int2* ep;
  if (b < SB1) {
    I = i1; V = v1; E = E1; cur = cur1; ep = ep1; nb = SB1;
  } else {
    I = i2; V = v2; E = E2; cur = cur2; ep = ep2; nb = SBtot - SB1; b -= SB1;
  }
  int g = b & 7;
  int bg = b >> 3;
  int chunk = (n + 7) >> 3;
  int lo = g * chunk;
  int hi = min(n, lo + chunk);
  int stride = (nb >> 3) * 256;
  for (int i = bg * 256 + threadIdx.x; i < E; i += stride) {
    int r = I[i];
    int c = I[E + i];
    float v = V[i];
    if (r >= lo && r < hi) {
      int p = atomicAdd(&cur[r], 1);
      int2 pk;
      pk.x = c;
      pk.y = __float_as_int(v);
      ep[p] = pk;
    }
  }
}

// ---------------- hop1: r0h (f16,[n,64]) -> r1 f32 + r1h f16 ----------
// One wave per output row; blocks [0,SB) -> graph1, [SB,2SB) -> graph2.
__global__ __launch_bounds__(256) void spmm_h1(
    const int* __restrict__ rs1, const int2* __restrict__ ep1,
    const int* __restrict__ rs2, const int2* __restrict__ ep2,
    const unsigned short* __restrict__ r0h, float* __restrict__ r1,
    unsigned short* __restrict__ r1h, int n, int SB) {
  const int* rs;
  const int2* epack;
  int coff;
  int blk = blockIdx.x;
  if (blk < SB) {
    rs = rs1; epack = ep1; coff = 0;
  } else {
    rs = rs2; epack = ep2; coff = 64; blk -= SB;
  }
  int lane = threadIdx.x & 63;
  int row = blk * 4 + (threadIdx.x >> 6);
  if (row >= n) return;
  int s = rs[row], e = rs[row + 1];
  float acc = 0.f;
  int j = s;
  for (; j + 8 <= e; j += 8) {
    int2 ep[8];
#pragma unroll
    for (int u = 0; u < 8; ++u) ep[u] = epack[j + u];
    float xg[8];
#pragma unroll
    for (int u = 0; u < 8; ++u) xg[u] = h2f(r0h[(size_t)ep[u].x * 64 + lane]);
#pragma unroll
    for (int u = 0; u < 8; ++u) acc = fmaf(__int_as_float(ep[u].y), xg[u], acc);
  }
  for (; j < e; ++j) {
    int2 ep = epack[j];
    acc = fmaf(__int_as_float(ep.y), h2f(r0h[(size_t)ep.x * 64 + lane]), acc);
  }
  float v = fmaxf(acc, 0.f);
  r1[(size_t)row * 128 + coff + lane] = v;
  r1h[(size_t)row * 128 + coff + lane] = f2h(v);
}

// ---------------- hop2: r1h (f16,[n,128]) -> r2 f32 -------------------
// One wave per output row, 2 features/lane (one 32-bit load = 2 f16).
__global__ __launch_bounds__(256) void spmm_h2(
    const int* __restrict__ rs1, const int2* __restrict__ ep1,
    const int* __restrict__ rs2, const int2* __restrict__ ep2,
    const unsigned short* __restrict__ r1h, float* __restrict__ r2, int n,
    int SB) {
  const int* rs;
  const int2* epack;
  int coff;
  int blk = blockIdx.x;
  if (blk < SB) {
    rs = rs1; epack = ep1; coff = 0;
  } else {
    rs = rs2; epack = ep2; coff = 128; blk -= SB;
  }
  int lane = threadIdx.x & 63;
  int row = blk * 4 + (threadIdx.x >> 6);
  if (row >= n) return;
  int s = rs[row], e = rs[row + 1];
  float acc0 = 0.f, acc1 = 0.f;
  int j = s;
  for (; j + 8 <= e; j += 8) {
    int2 ep[8];
#pragma unroll
    for (int u = 0; u < 8; ++u) ep[u] = epack[j + u];
    unsigned g[8];
#pragma unroll
    for (int u = 0; u < 8; ++u)
      g[u] = *(const unsigned*)&r1h[(size_t)ep[u].x * 128 + lane * 2];
#pragma unroll
    for (int u = 0; u < 8; ++u) {
      float v = __int_as_float(ep[u].y);
      acc0 = fmaf(v, h2f((unsigned short)(g[u] & 0xFFFF)), acc0);
      acc1 = fmaf(v, h2f((unsigned short)(g[u] >> 16)), acc1);
    }
  }
  for (; j < e; ++j) {
    int2 ep = epack[j];
    unsigned g = *(const unsigned*)&r1h[(size_t)ep.x * 128 + lane * 2];
    float v = __int_as_float(ep.y);
    acc0 = fmaf(v, h2f((unsigned short)(g & 0xFFFF)), acc0);
    acc1 = fmaf(v, h2f((unsigned short)(g >> 16)), acc1);
  }
  float2 st;
  st.x = fmaxf(acc0, 0.f);
  st.y = fmaxf(acc1, 0.f);
  *(float2*)&r2[(size_t)row * 256 + coff + lane * 2] = st;
}

// ---------------- classifier + softmax --------------------------------
// wls padded to stride 17: removes the 4-way LDS bank conflict (4 parts per
// wave previously hit the same 16 banks on every read).
__global__ __launch_bounds__(256) void classify_softmax(
    const float* __restrict__ r0, const float* __restrict__ r1,
    const float* __restrict__ r2, const float* __restrict__ wc,
    float* __restrict__ out, int n) {
  __shared__ float wls[448 * 17];  // ~29.8 KB
  for (int i = threadIdx.x; i < 448 * 16; i += 256)
    wls[(i >> 4) * 17 + (i & 15)] = wc[i];
  __syncthreads();
  int lane = threadIdx.x & 63;
  int c = lane & 15;
  int part = lane >> 4;
  int node = blockIdx.x * 4 + (threadIdx.x >> 6);
  if (node >= n) return;

  float acc = 0.f;
  {
    const float* p = r0 + (size_t)node * 64 + part * 16;
#pragma unroll
    for (int j = 0; j < 4; ++j) {
      float4 rv = *(const float4*)(p + 4 * j);
      int fb = part * 16 + 4 * j;
      acc = fmaf(rv.x, wls[(fb + 0) * 17 + c], acc);
      acc = fmaf(rv.y, wls[(fb + 1) * 17 + c], acc);
      acc = fmaf(rv.z, wls[(fb + 2) * 17 + c], acc);
      acc = fmaf(rv.w, wls[(fb + 3) * 17 + c], acc);
    }
  }
  {
    const float* p = r1 + (size_t)node * 128 + part * 32;
#pragma unroll
    for (int j = 0; j < 8; ++j) {
      float4 rv = *(const float4*)(p + 4 * j);
      int fb = 64 + part * 32 + 4 * j;
      acc = fmaf(rv.x, wls[(fb + 0) * 17 + c], acc);
      acc = fmaf(rv.y, wls[(fb + 1) * 17 + c], acc);
      acc = fmaf(rv.z, wls[(fb + 2) * 17 + c], acc);
      acc = fmaf(rv.w, wls[(fb + 3) * 17 + c], acc);
    }
  }
  {
    const float* p = r2 + (size_t)node * 256 + part * 64;
#pragma unroll
    for (int j = 0; j < 16; ++j) {
      float4 rv = *(const float4*)(p + 4 * j);
      int fb = 192 + part * 64 + 4 * j;
      acc = fmaf(rv.x, wls[(fb + 0) * 17 + c], acc);
      acc = fmaf(rv.y, wls[(fb + 1) * 17 + c], acc);
      acc = fmaf(rv.z, wls[(fb + 2) * 17 + c], acc);
      acc = fmaf(rv.w, wls[(fb + 3) * 17 + c], acc);
    }
  }
  acc += __shfl_xor(acc, 16, 64);
  acc += __shfl_xor(acc, 32, 64);
  float m = acc;
#pragma unroll
  for (int d = 1; d < 16; d <<= 1) m = fmaxf(m, __shfl_xor(m, d, 64));
  float ex = __expf(acc - m);
  float s = ex;
#pragma unroll
  for (int d = 1; d < 16; d <<= 1) s += __shfl_xor(s, d, 64);
  if (lane < 16) out[(size_t)node * 16 + c] = ex / s;
}

extern "C" void kernel_launch(void* const* d_in, const int* in_sizes, int n_in,
                              void* d_out, int out_size, void* d_ws, size_t ws_size,
                              hipStream_t stream) {
  const float* x = (const float*)d_in[0];
  const int* a1_idx = (const int*)d_in[1];
  const float* a1_val = (const float*)d_in[2];
  const int* a2_idx = (const int*)d_in[3];
  const float* a2_val = (const float*)d_in[4];
  const float* w_embed = (const float*)d_in[5];
  const float* w_classify = (const float*)d_in[6];
  float* out = (float*)d_out;

  const int n = in_sizes[0] / F_IN;  // 50000
  const int E1 = in_sizes[2];        // 800000
  const int E2 = in_sizes[4];        // 1600000

  // workspace layout
  float* r0 = (float*)d_ws;                        // n*64 f32
  float* r1 = r0 + (size_t)n * 64;                 // n*128 f32
  float* r2 = r1 + (size_t)n * 128;                // n*256 f32
  unsigned short* r0h = (unsigned short*)(r2 + (size_t)n * 256);  // n*64 f16
  unsigned short* r1h = r0h + (size_t)n * 64;      // n*128 f16
  int* cnt1 = (int*)(r1h + (size_t)n * 128);       // n
  int* cnt2 = cnt1 + n;                            // n
  int* rs1 = cnt2 + n;                             // n+1
  int* rs2 = rs1 + (n + 1);                        // n+1
  int* cur1 = rs2 + (n + 1);                       // n
  int* cur2 = cur1 + n;                            // n
  int* aux1 = cur2 + n;                            // 512
  int* aux2 = aux1 + 512;                          // 512
  int2* ep1 = (int2*)(aux2 + 512);                 // E1 (8B each)
  int2* ep2 = ep1 + E1;                            // E2

  auto blocks = [](long long t, int bs) { return (int)((t + bs - 1) / bs); };
  const int NB = blocks(n, 512);     // 98
  const int HB1 = blocks(E1, 256);   // 3125
  const int HB2 = blocks(E2, 256);   // 6250
  const int SC1 = 1024, SC2 = 2048;  // scatter blocks (mult of 8)
  const int SB = blocks(n, 4);       // spmm blocks per graph

  // embed (independent of CSR build)
  embed_gemm_relu<<<blocks(n / 4, 4), 256, 0, stream>>>(x, w_embed, r0, r0h,
                                                        n / 4);

  // CSR build for both graphs (fused per stage)
  hipMemsetAsync(cnt1, 0, (size_t)2 * n * sizeof(int), stream);
  histo2<<<HB1 + HB2, 256, 0, stream>>>(a1_idx, E1, cnt1, a2_idx, E2, cnt2, HB1);
  scan_blocks2<<<2 * NB, 512, 0, stream>>>(cnt1, rs1, aux1, cnt2, rs2, aux2, n, NB);
  scan_aux2<<<2, 512, 0, stream>>>(aux1, aux2, NB);
  add_offsets2<<<2 * NB, 512, 0, stream>>>(rs1, cur1, aux1, E1, rs2, cur2, aux2,
                                           E2, n, NB);
  scatter_ranged<<<SC1 + SC2, 256, 0, stream>>>(a1_idx, a1_val, E1, cur1, ep1,
                                                a2_idx, a2_val, E2, cur2, ep2,
                                                SC1, SC1 + SC2, n);

  // hop 1: r0h -> r1 [n,128] f32 + r1h f16  (ReLU fused)
  spmm_h1<<<2 * SB, 256, 0, stream>>>(rs1, ep1, rs2, ep2, r0h, r1, r1h, n, SB);
  // hop 2: r1h -> r2 [n,256] f32  (ReLU fused)
  spmm_h2<<<2 * SB, 256, 0, stream>>>(rs1, ep1, rs2, ep2, r1h, r2, n, SB);

  classify_softmax<<<blocks(n, 4), 256, 0, stream>>>(r0, r1, r2, w_classify, out, n);
}